// Round 6
// baseline (5683.918 us; speedup 1.0000x reference)
//
#include <hip/hip_runtime.h>

#define B_ 4096
#define S_ 24
#define T_ 32
#define V_ 120
#define E_ 128
#define HE_ 512
#define HD_ 512
#define START_TOK 2

typedef __attribute__((ext_vector_type(8))) __bf16 bf16x8;
typedef __attribute__((ext_vector_type(8))) short s16x8;
typedef __attribute__((ext_vector_type(4))) float f32x4;
typedef unsigned short u16;

static __device__ __forceinline__ u16 f2bf(float f) {
  union { float f; unsigned u; } v; v.f = f;
  unsigned r = v.u + 0x7FFFu + ((v.u >> 16) & 1u);
  return (u16)(r >> 16);
}
static __device__ __forceinline__ float bf2f(u16 h) {
  union { unsigned u; float f; } v; v.u = ((unsigned)h) << 16;
  return v.f;
}
static __device__ __forceinline__ float sigm(float x) {
  return 1.f / (1.f + __expf(-x));
}

// ---------------- setup kernels (f32 -> bf16) ----------------
__global__ void cvt_f2b(const float* __restrict__ src, u16* __restrict__ dst,
                        int n, size_t src_off) {
  for (int i = blockIdx.x * blockDim.x + threadIdx.x; i < n;
       i += gridDim.x * blockDim.x) {
    float2 v = *(const float2*)(src + src_off + (size_t)i * 2);
    dst[(size_t)i * 2]     = f2bf(v.x);
    dst[(size_t)i * 2 + 1] = f2bf(v.y);
  }
}

// src[512][512] f32 -> dst[512][512] transposed bf16
__global__ void cvt_transpose(const float* __restrict__ src, u16* __restrict__ dst) {
  int i = blockIdx.x * blockDim.x + threadIdx.x;
  if (i < 512 * 512) {
    int r = i >> 9, c = i & 511;
    dst[c * 512 + r] = f2bf(src[i]);
  }
}

// W_out (120x512) f32 -> padded (128x512) bf16 ; b_out (120) f32 -> padded f32 (128)
__global__ void cvt_pad_wout(const float* __restrict__ w, const float* __restrict__ b,
                             u16* __restrict__ wp, float* __restrict__ bp) {
  int i = blockIdx.x * blockDim.x + threadIdx.x;
  if (i < 128 * 512) {
    int n = i >> 9, k = i & 511;
    wp[i] = (n < V_) ? f2bf(w[n * 512 + k]) : (u16)0;
  }
  if (i < 128) bp[i] = (i < V_) ? b[i] : 0.f;
}

__global__ void bias_sum(const float* __restrict__ a, const float* __restrict__ b,
                         float* __restrict__ dst, int n) {
  int i = blockIdx.x * blockDim.x + threadIdx.x;
  if (i < n) dst[i] = a[i] + b[i];
}

// ---------------- generic MFMA GEMM ----------------
// C[M,NN] = act(A[M,KK] @ Bt[NN,KK]^T + bias)
// Block = 64M x 64N, 4 waves (2x2), wave tile 32x32 (2x2 of 16x16x32 frags).
// AMODE: 0 = A bf16 contiguous; 2 = A concat(A0 K=512, A1 K=512)
// ACT: 0 none, 1 tanh ; OUTF: 0 bf16 out, 1 f32 out
// LOOPN: 1 -> single grid.y, loop all N-slabs in-kernel (A stays in L2)
template<int AMODE, int ACT, int OUTF, int KK, int NN, int LOOPN>
__global__ __launch_bounds__(256) void mfma_gemm(
    const u16* __restrict__ A0, const u16* __restrict__ A1,
    const u16* __restrict__ Bt, const float* __restrict__ bias,
    void* __restrict__ Cv, int M)
{
  int lane = threadIdx.x & 63, wv = threadIdx.x >> 6;
  int wm = wv >> 1, wn = wv & 1;
  int mb = blockIdx.x * 64 + wm * 32;
  int lr = lane & 15, lk = (lane >> 4) * 8;
  int rhi = lane >> 4;

  const int NOUT = LOOPN ? (NN / 64) : 1;
#pragma unroll 1
  for (int no = 0; no < NOUT; no++) {
    int nb = (LOOPN ? no * 64 : blockIdx.y * 64) + wn * 32;
    f32x4 acc[2][2] = {};

#pragma unroll
    for (int k0 = 0; k0 < KK; k0 += 32) {
      int kk = k0 + lk;
      bf16x8 af[2], bfr[2];
#pragma unroll
      for (int a = 0; a < 2; a++) {
        int m = mb + a * 16 + lr;
        if constexpr (AMODE == 0) {
          af[a] = *(const bf16x8*)(A0 + (size_t)m * KK + kk);
        } else {
          const u16* src = (kk < 512) ? (A0 + (size_t)m * 512 + kk)
                                      : (A1 + (size_t)m * 512 + (kk - 512));
          af[a] = *(const bf16x8*)src;
        }
      }
#pragma unroll
      for (int bb = 0; bb < 2; bb++) {
        int n = nb + bb * 16 + lr;
        bfr[bb] = *(const bf16x8*)(Bt + (size_t)n * KK + kk);
      }
#pragma unroll
      for (int a = 0; a < 2; a++)
#pragma unroll
        for (int bb = 0; bb < 2; bb++)
          acc[a][bb] = __builtin_amdgcn_mfma_f32_16x16x32_bf16(af[a], bfr[bb], acc[a][bb], 0, 0, 0);
    }

#pragma unroll
    for (int a = 0; a < 2; a++)
#pragma unroll
      for (int bb = 0; bb < 2; bb++) {
        int n = nb + bb * 16 + lr;
        float bv = bias ? bias[n] : 0.f;
#pragma unroll
        for (int r = 0; r < 4; r++) {
          int m = mb + a * 16 + rhi * 4 + r;
          float v = acc[a][bb][r] + bv;
          if constexpr (ACT == 1) v = tanhf(v);
          if constexpr (OUTF == 1) ((float*)Cv)[(size_t)m * NN + n] = v;
          else                     ((u16*)Cv)[(size_t)m * NN + n] = f2bf(v);
        }
      }
  }
}

// ---------------- fused gates GEMM + LSTM pointwise ----------------
__global__ __launch_bounds__(256) void gates_lstm_kernel(
    const u16* __restrict__ emb_b, const int* __restrict__ target,
    const u16* __restrict__ wih, const u16* __restrict__ whh,
    const float* __restrict__ bsum,
    const u16* __restrict__ h_in, u16* __restrict__ h_out,
    float* __restrict__ c, int t)
{
  int lane = threadIdx.x & 63, wv = threadIdx.x >> 6;
  int mb = blockIdx.x * 128 + wv * 32;
  int db = blockIdx.y * 32;
  int lr = lane & 15, lk = (lane >> 4) * 8;

  int tok[2];
#pragma unroll
  for (int a = 0; a < 2; a++) {
    int m = mb + a * 16 + lr;
    tok[a] = (t == 0) ? START_TOK : target[m * T_ + (t - 1)];
  }

  f32x4 acc[4][2][2] = {};  // [gate][a][bb]

#pragma unroll
  for (int k0 = 0; k0 < 128; k0 += 32) {
    int kk = k0 + lk;
    bf16x8 af[2], bfr[4][2];
#pragma unroll
    for (int a = 0; a < 2; a++)
      af[a] = *(const bf16x8*)(emb_b + tok[a] * E_ + kk);
#pragma unroll
    for (int g = 0; g < 4; g++)
#pragma unroll
      for (int bb = 0; bb < 2; bb++) {
        int n = (g << 9) + db + bb * 16 + lr;
        bfr[g][bb] = *(const bf16x8*)(wih + (size_t)n * E_ + kk);
      }
#pragma unroll
    for (int g = 0; g < 4; g++)
#pragma unroll
      for (int a = 0; a < 2; a++)
#pragma unroll
        for (int bb = 0; bb < 2; bb++)
          acc[g][a][bb] = __builtin_amdgcn_mfma_f32_16x16x32_bf16(af[a], bfr[g][bb], acc[g][a][bb], 0, 0, 0);
  }
#pragma unroll
  for (int k0 = 0; k0 < 512; k0 += 32) {
    int kk = k0 + lk;
    bf16x8 af[2], bfr[4][2];
#pragma unroll
    for (int a = 0; a < 2; a++) {
      int m = mb + a * 16 + lr;
      af[a] = *(const bf16x8*)(h_in + (size_t)m * HD_ + kk);
    }
#pragma unroll
    for (int g = 0; g < 4; g++)
#pragma unroll
      for (int bb = 0; bb < 2; bb++) {
        int n = (g << 9) + db + bb * 16 + lr;
        bfr[g][bb] = *(const bf16x8*)(whh + (size_t)n * HD_ + kk);
      }
#pragma unroll
    for (int g = 0; g < 4; g++)
#pragma unroll
      for (int a = 0; a < 2; a++)
#pragma unroll
        for (int bb = 0; bb < 2; bb++)
          acc[g][a][bb] = __builtin_amdgcn_mfma_f32_16x16x32_bf16(af[a], bfr[g][bb], acc[g][a][bb], 0, 0, 0);
  }

  int rhi = lane >> 4;
#pragma unroll
  for (int a = 0; a < 2; a++)
#pragma unroll
    for (int bb = 0; bb < 2; bb++) {
      int d = db + bb * 16 + lr;
      float bi  = bsum[d];
      float bfv = bsum[512 + d];
      float bg  = bsum[1024 + d];
      float bo  = bsum[1536 + d];
#pragma unroll
      for (int r = 0; r < 4; r++) {
        int m = mb + a * 16 + rhi * 4 + r;
        size_t idx = (size_t)m * HD_ + d;
        float iv = acc[0][a][bb][r] + bi;
        float fv = acc[1][a][bb][r] + bfv;
        float gv = acc[2][a][bb][r] + bg;
        float ov = acc[3][a][bb][r] + bo;
        float cold = c[idx];
        float cn = sigm(fv) * cold + sigm(iv) * tanhf(gv);
        c[idx] = cn;
        h_out[idx] = f2bf(sigm(ov) * tanhf(cn));
      }
    }
}

// ---------------- attention: score + softmax + ctx ----------------
__global__ __launch_bounds__(256) void score_ctx_kernel(
    const u16* __restrict__ enc_proj, const u16* __restrict__ encB,
    const u16* __restrict__ qb, const float* __restrict__ v_attn,
    float* __restrict__ attn_out, float* __restrict__ attn_ws,
    u16* __restrict__ ctx_bf, int t)
{
  int b = blockIdx.x;
  int tid = threadIdx.x, lane = tid & 63, w = tid >> 6;
  __shared__ float s_att[S_];
  __shared__ float s_sc[S_];

  float qreg[8], vreg[8];
  const u16* qp = qb + (size_t)b * HD_ + lane * 8;
#pragma unroll
  for (int j = 0; j < 8; j++) { qreg[j] = bf2f(qp[j]); vreg[j] = v_attn[lane * 8 + j]; }

  const u16* epb = enc_proj + (size_t)b * S_ * HD_;
  float myscore[6];
#pragma unroll
  for (int i = 0; i < 6; i++) {
    int s = w * 6 + i;
    s16x8 ev = *(const s16x8*)(epb + (size_t)s * HD_ + lane * 8);
    float p = 0.f;
#pragma unroll
    for (int j = 0; j < 8; j++) p += vreg[j] * tanhf(bf2f((u16)ev[j]) + qreg[j]);
#pragma unroll
    for (int m = 1; m < 64; m <<= 1) p += __shfl_xor(p, m, 64);
    myscore[i] = p;
  }
  if (lane == 0) {
#pragma unroll
    for (int i = 0; i < 6; i++) s_sc[w * 6 + i] = myscore[i];
  }
  __syncthreads();

  float mx = -1e30f;
#pragma unroll
  for (int s = 0; s < S_; s++) mx = fmaxf(mx, s_sc[s]);
  if (tid < S_) s_att[tid] = __expf(s_sc[tid] - mx);
  __syncthreads();
  float sum = 0.f;
#pragma unroll
  for (int s = 0; s < S_; s++) sum += s_att[s];
  float inv = 1.f / sum;
  if (tid < S_) {
    float a = s_att[tid] * inv;
    attn_out[((size_t)b * T_ + t) * S_ + tid] = a;
    attn_ws[b * S_ + tid] = a;
  }

  // ctx: each thread handles 2 dims via one packed u32 per s
  float c0 = 0.f, c1 = 0.f;
  const unsigned* eb = (const unsigned*)(encB + (size_t)b * S_ * HE_) + tid;
#pragma unroll
  for (int s = 0; s < S_; s++) {
    unsigned v = eb[s * (HE_ / 2)];
    float a = s_att[s] * inv;
    c0 += a * bf2f((u16)(v & 0xFFFFu));
    c1 += a * bf2f((u16)(v >> 16));
  }
  ctx_bf[(size_t)b * HE_ + tid * 2]     = f2bf(c0);
  ctx_bf[(size_t)b * HE_ + tid * 2 + 1] = f2bf(c1);
}

// ---------------- output head: softmax + pointer-copy ----------------
__global__ __launch_bounds__(128) void out_kernel(
    const float* __restrict__ logits, const u16* __restrict__ ah,
    const u16* __restrict__ ctxb, const float* __restrict__ w_copy,
    const float* __restrict__ b_copy, const float* __restrict__ attn_ws,
    const int* __restrict__ input_ids, float* __restrict__ outp, int t)
{
  int b = blockIdx.x;
  int tid = threadIdx.x, lane = tid & 63, w = tid >> 6;
  __shared__ float s_l[V_], s_copy[V_], s_small[8];

  float part = 0.f;
  {
    int base = tid * 8;
    const u16* src = (base < 512) ? (ah + (size_t)b * HD_ + base)
                                  : (ctxb + (size_t)b * HE_ + (base - 512));
#pragma unroll
    for (int j = 0; j < 8; j++) part += bf2f(src[j]) * w_copy[base + j];
  }
#pragma unroll
  for (int m = 1; m < 64; m <<= 1) part += __shfl_xor(part, m, 64);
  if (lane == 0) s_small[w] = part;

  if (tid < V_) { s_l[tid] = logits[(size_t)b * 128 + tid]; s_copy[tid] = 0.f; }
  __syncthreads();

  if (tid < S_) atomicAdd(&s_copy[input_ids[b * S_ + tid]], attn_ws[b * S_ + tid]);

  float pc_dot = s_small[0] + s_small[1];
  float pcopy = sigm(pc_dot + b_copy[0]);

  float lv = (tid < V_) ? s_l[tid] : -1e30f;
  float wmx = lv;
#pragma unroll
  for (int m = 1; m < 64; m <<= 1) wmx = fmaxf(wmx, __shfl_xor(wmx, m, 64));
  if (lane == 0) s_small[2 + w] = wmx;
  __syncthreads();
  float mx = fmaxf(s_small[2], s_small[3]);
  float ex = (tid < V_) ? __expf(lv - mx) : 0.f;
  float wsum = ex;
#pragma unroll
  for (int m = 1; m < 64; m <<= 1) wsum += __shfl_xor(wsum, m, 64);
  if (lane == 0) s_small[4 + w] = wsum;
  __syncthreads();
  float inv = 1.f / (s_small[4] + s_small[5]);

  if (tid < V_) {
    float vocab = ex * inv;
    float o = (1.f - pcopy) * vocab + pcopy * s_copy[tid];
    outp[((size_t)b * T_ + t) * V_ + tid] = o;
  }
}

// ---------------- launch ----------------
extern "C" void kernel_launch(void* const* d_in, const int* in_sizes, int n_in,
                              void* d_out, int out_size, void* d_ws, size_t ws_size,
                              hipStream_t stream)
{
  const float* enc      = (const float*)d_in[0];
  const float* enc_fin  = (const float*)d_in[1];
  const int*   target   = (const int*)d_in[2];
  const int*   input_ids= (const int*)d_in[3];
  const float* embed    = (const float*)d_in[4];
  const float* W_init   = (const float*)d_in[5];
  const float* b_init   = (const float*)d_in[6];
  const float* W_ih     = (const float*)d_in[7];
  const float* W_hh     = (const float*)d_in[8];
  const float* b_ih     = (const float*)d_in[9];
  const float* b_hh     = (const float*)d_in[10];
  const float* W_enc    = (const float*)d_in[11];
  const float* W_dec    = (const float*)d_in[12];
  const float* b_attn   = (const float*)d_in[13];
  const float* v_attn   = (const float*)d_in[14];
  const float* W_ap     = (const float*)d_in[15];
  const float* b_ap     = (const float*)d_in[16];
  const float* W_out    = (const float*)d_in[17];
  const float* b_out    = (const float*)d_in[18];
  const float* w_copy   = (const float*)d_in[19];
  const float* b_copy   = (const float*)d_in[20];
  float* outp = (float*)d_out;
  float* attn_out_g = outp + (size_t)B_ * T_ * V_;

  // --- pick chunk count from ws_size ---
  auto align256 = [](size_t x) { return (x + 255) & ~(size_t)255; };
  const size_t persist =
      align256(512 * 512 * 2) * 2 +      // wencT, wdecT
      align256(128 * 512 * 2) +          // woutp
      align256(128 * 4) +                // boutp
      align256(2048 * 4) +               // bsum
      align256((size_t)V_ * E_ * 2) +    // embB
      align256((size_t)512 * 512 * 2) +  // winitB
      align256((size_t)2048 * 128 * 2) + // wihB
      align256((size_t)2048 * 512 * 2) + // whhB
      align256((size_t)512 * 1024 * 2) + // wapB
      align256((size_t)B_ * HE_ * 2);    // encfinB
  auto perchunk = [&](int CB) -> size_t {
    return align256((size_t)CB * S_ * HE_ * 2) +   // encB
           align256((size_t)CB * S_ * HD_ * 2) +   // encproj
           align256((size_t)CB * HD_ * 2) * 2 +    // h0,h1
           align256((size_t)CB * HD_ * 4) +        // cbuf
           align256((size_t)CB * HD_ * 2) * 3 +    // q, ctx, ah
           align256((size_t)CB * 128 * 4) +        // logits
           align256((size_t)CB * S_ * 4);          // attnws
  };
  int NC = 16;
  for (int c : {1, 2, 4, 8, 16}) {
    if (persist + perchunk(B_ / c) <= ws_size) { NC = c; break; }
  }
  const int CB = B_ / NC;

  char* ws = (char*)d_ws;
  size_t off = 0;
  auto alloc = [&](size_t bytes) -> char* {
    char* p = ws + off; off += align256(bytes); return p;
  };
  u16*   wencT   = (u16*)alloc(512 * 512 * 2);
  u16*   wdecT   = (u16*)alloc(512 * 512 * 2);
  u16*   woutp   = (u16*)alloc(128 * 512 * 2);
  float* boutp   = (float*)alloc(128 * 4);
  float* bsum    = (float*)alloc(2048 * 4);
  u16*   embB    = (u16*)alloc((size_t)V_ * E_ * 2);
  u16*   winitB  = (u16*)alloc((size_t)512 * 512 * 2);
  u16*   wihB    = (u16*)alloc((size_t)2048 * 128 * 2);
  u16*   whhB    = (u16*)alloc((size_t)2048 * 512 * 2);
  u16*   wapB    = (u16*)alloc((size_t)512 * 1024 * 2);
  u16*   encfinB = (u16*)alloc((size_t)B_ * HE_ * 2);
  u16*   encB    = (u16*)alloc((size_t)CB * S_ * HE_ * 2);
  u16*   encproj = (u16*)alloc((size_t)CB * S_ * HD_ * 2);
  u16*   hbuf0   = (u16*)alloc((size_t)CB * HD_ * 2);
  u16*   hbuf1   = (u16*)alloc((size_t)CB * HD_ * 2);
  float* cbuf    = (float*)alloc((size_t)CB * HD_ * 4);
  u16*   qbuf    = (u16*)alloc((size_t)CB * HD_ * 2);
  u16*   ctxbuf  = (u16*)alloc((size_t)CB * HD_ * 2);
  u16*   ahbuf   = (u16*)alloc((size_t)CB * HD_ * 2);
  float* logitsb = (float*)alloc((size_t)CB * 128 * 4);
  float* attnws  = (float*)alloc((size_t)CB * S_ * 4);

  auto cdiv = [](int a, int b) { return (a + b - 1) / b; };
  auto cgrid2 = [&](int n2) { int g = cdiv(n2, 256); return g > 2048 ? 2048 : g; };

  // --- setup: convert weights to bf16 (pairs per thread) ---
  cvt_f2b<<<cgrid2(V_ * E_ / 2), 256, 0, stream>>>(embed, embB, V_ * E_ / 2, 0);
  cvt_f2b<<<cgrid2(512 * 512 / 2), 256, 0, stream>>>(W_init, winitB, 512 * 512 / 2, 0);
  cvt_f2b<<<cgrid2(2048 * 128 / 2), 256, 0, stream>>>(W_ih, wihB, 2048 * 128 / 2, 0);
  cvt_f2b<<<cgrid2(2048 * 512 / 2), 256, 0, stream>>>(W_hh, whhB, 2048 * 512 / 2, 0);
  cvt_f2b<<<cgrid2(512 * 1024 / 2), 256, 0, stream>>>(W_ap, wapB, 512 * 1024 / 2, 0);
  cvt_f2b<<<cgrid2(B_ * HE_ / 2), 256, 0, stream>>>(enc_fin, encfinB, B_ * HE_ / 2, 0);
  cvt_transpose<<<cdiv(512 * 512, 256), 256, 0, stream>>>(W_enc, wencT);
  cvt_transpose<<<cdiv(512 * 512, 256), 256, 0, stream>>>(W_dec, wdecT);
  cvt_pad_wout<<<cdiv(128 * 512, 256), 256, 0, stream>>>(W_out, b_out, woutp, boutp);
  bias_sum<<<8, 256, 0, stream>>>(b_ih, b_hh, bsum, 2048);

  u16* hb[2] = { hbuf0, hbuf1 };
  for (int c = 0; c < NC; c++) {
    const size_t row0 = (size_t)c * CB;
    // chunk enc -> bf16
    cvt_f2b<<<2048, 256, 0, stream>>>(enc, encB, CB * S_ * HE_ / 2,
                                      row0 * S_ * HE_);
    // enc_proj = enc @ W_enc_attn  (full-N loop: A read from HBM once)
    mfma_gemm<0, 0, 0, 512, 512, 1><<<dim3(CB * S_ / 64), 256, 0, stream>>>(
        encB, nullptr, wencT, nullptr, encproj, CB * S_);
    // h0 = enc_final @ W_init^T + b_init
    mfma_gemm<0, 0, 0, 512, 512, 0><<<dim3(CB / 64, 8), 256, 0, stream>>>(
        encfinB + row0 * HE_, nullptr, winitB, b_init, hbuf0, CB);
    hipMemsetAsync(cbuf, 0, (size_t)CB * HD_ * 4, stream);

    for (int t = 0; t < T_; t++) {
      u16* hprev = hb[t & 1];
      u16* hnew  = hb[(t + 1) & 1];
      gates_lstm_kernel<<<dim3(CB / 128, HD_ / 32), 256, 0, stream>>>(
          embB, target + row0 * T_, wihB, whhB, bsum, hprev, hnew, cbuf, t);
      // q = h @ W_dec_attn + b_attn
      mfma_gemm<0, 0, 0, 512, 512, 0><<<dim3(CB / 64, 8), 256, 0, stream>>>(
          hnew, nullptr, wdecT, b_attn, qbuf, CB);
      score_ctx_kernel<<<CB, 256, 0, stream>>>(
          encproj, encB, qbuf, v_attn,
          attn_out_g + row0 * T_ * S_, attnws, ctxbuf, t);
      // ah = tanh([h, ctx] @ W_ap^T + b_ap)
      mfma_gemm<2, 1, 0, 1024, 512, 0><<<dim3(CB / 64, 8), 256, 0, stream>>>(
          hnew, ctxbuf, wapB, b_ap, ahbuf, CB);
      // logits = ah @ W_out_pad^T + b_out_pad (f32 out, N=128)
      mfma_gemm<0, 0, 1, 512, 128, 0><<<dim3(CB / 64, 2), 256, 0, stream>>>(
          ahbuf, nullptr, woutp, boutp, logitsb, CB);
      out_kernel<<<CB, 128, 0, stream>>>(
          logitsb, ahbuf, ctxbuf, w_copy, b_copy, attnws,
          input_ids + row0 * S_, outp + row0 * T_ * V_, t);
    }
  }
  (void)in_sizes; (void)n_in; (void)out_size;
}

// Round 8
// 3748.788 us; speedup vs baseline: 1.5162x; 1.5162x over previous
//
#include <hip/hip_runtime.h>

#define B_ 4096
#define S_ 24
#define T_ 32
#define V_ 120
#define E_ 128
#define HE_ 512
#define HD_ 512
#define START_TOK 2

typedef __attribute__((ext_vector_type(8))) __bf16 bf16x8;
typedef __attribute__((ext_vector_type(8))) short s16x8;
typedef __attribute__((ext_vector_type(4))) float f32x4;
typedef unsigned short u16;

static __device__ __forceinline__ u16 f2bf(float f) {
  union { float f; unsigned u; } v; v.f = f;
  unsigned r = v.u + 0x7FFFu + ((v.u >> 16) & 1u);
  return (u16)(r >> 16);
}
static __device__ __forceinline__ float bf2f(u16 h) {
  union { unsigned u; float f; } v; v.u = ((unsigned)h) << 16;
  return v.f;
}
static __device__ __forceinline__ float sigm(float x) {
  return 1.f / (1.f + __expf(-x));
}
static __device__ __forceinline__ void gl16(const void* g, void* l) {
  __builtin_amdgcn_global_load_lds(
      (const __attribute__((address_space(1))) void*)g,
      (__attribute__((address_space(3))) void*)l, 16, 0, 0);
}

// ---------------- setup kernels (f32 -> bf16) ----------------
__global__ void cvt_f2b(const float* __restrict__ src, u16* __restrict__ dst,
                        int n, size_t src_off) {
  for (int i = blockIdx.x * blockDim.x + threadIdx.x; i < n;
       i += gridDim.x * blockDim.x) {
    float2 v = *(const float2*)(src + src_off + (size_t)i * 2);
    dst[(size_t)i * 2]     = f2bf(v.x);
    dst[(size_t)i * 2 + 1] = f2bf(v.y);
  }
}

__global__ void cvt_transpose(const float* __restrict__ src, u16* __restrict__ dst) {
  int i = blockIdx.x * blockDim.x + threadIdx.x;
  if (i < 512 * 512) {
    int r = i >> 9, c = i & 511;
    dst[c * 512 + r] = f2bf(src[i]);
  }
}

__global__ void cvt_pad_wout(const float* __restrict__ w, const float* __restrict__ b,
                             u16* __restrict__ wp, float* __restrict__ bp) {
  int i = blockIdx.x * blockDim.x + threadIdx.x;
  if (i < 128 * 512) {
    int n = i >> 9, k = i & 511;
    wp[i] = (n < V_) ? f2bf(w[n * 512 + k]) : (u16)0;
  }
  if (i < 128) bp[i] = (i < V_) ? b[i] : 0.f;
}

__global__ void bias_sum(const float* __restrict__ a, const float* __restrict__ b,
                         float* __restrict__ dst, int n) {
  int i = blockIdx.x * blockDim.x + threadIdx.x;
  if (i < n) dst[i] = a[i] + b[i];
}

// gate-interleaved concat weight: wgI[n'][k], n' = (d>>4)*64 + g*16 + (d&15),
// k<128 from W_ih[g*512+d][k], else W_hh[g*512+d][k-128]
__global__ void cvt_gates_w(const float* __restrict__ wih, const float* __restrict__ whh,
                            u16* __restrict__ wgI) {
  for (int i = blockIdx.x * blockDim.x + threadIdx.x; i < 2048 * 640;
       i += gridDim.x * blockDim.x) {
    int np = i / 640, k = i - np * 640;
    int g = (np >> 4) & 3;
    int d = ((np >> 6) << 4) | (np & 15);
    float v = (k < 128) ? wih[(g * 512 + d) * 128 + k]
                        : whh[(size_t)(g * 512 + d) * 512 + (k - 128)];
    wgI[i] = f2bf(v);
  }
}

// ---------------- LDS-staged MFMA GEMM (m97 structure) ----------------
// C[M,NN] = act(A[M,KK] @ Bt[NN,KK]^T + bias)
// Block: 256 threads (4 waves, 2x2), tile BM x 128, BK=64, single-buffer LDS,
// global_load_lds staging with XOR-swizzle ((row&7)<<4 on byte within 128B row).
// AMODE: 0 = A contiguous [M][KK]; 2 = concat(A0[M][512], A1[M][512]);
//        3 = gates: k<128 -> embB[tok(m)][k], else A1(h)[m][k-128]
// GATES=1: fused LSTM epilogue (bias=bsum, writes h_out/cstate), Cv unused.
template<int BM, int AMODE, int ACT, int OUTF, int KK, int NN, int GATES>
__global__ __launch_bounds__(256) void gemm_lds(
    const u16* __restrict__ A0, const u16* __restrict__ A1,
    const u16* __restrict__ Bt, const float* __restrict__ bias,
    void* __restrict__ Cv,
    const int* __restrict__ target, int t,
    u16* __restrict__ h_out, float* __restrict__ cstate)
{
  __shared__ u16 lA[BM * 64];
  __shared__ u16 lB[128 * 64];

  const int tid = threadIdx.x;
  const int lane = tid & 63, wv = tid >> 6;
  const int wm = wv >> 1, wn = wv & 1;
  const int mb = blockIdx.x * BM;
  const int nb = blockIdx.y * 128;
  const int lr = lane & 15, lk = (lane >> 4) * 8;
  const int rhi = lane >> 4;
  const int MA = BM / 64 * 2;  // m-frags per wave (BM=128 -> 4, BM=64 -> 2)

  f32x4 acc[MA][4] = {};

  // staging thread mapping (per pass of 4096 B): row = p*32 + tid>>3
  const int srow = tid >> 3;
  const int cbd = (tid & 7) * 16;  // dest col-byte within 128B row

#pragma unroll 1
  for (int kt = 0; kt < KK / 64; kt++) {
    if (kt > 0) __syncthreads();
    // ---- stage A (BM/32 passes) ----
#pragma unroll
    for (int p = 0; p < BM / 32; p++) {
      int row = p * 32 + srow;
      int cbs = cbd ^ ((row & 7) << 4);
      int k = kt * 64 + (cbs >> 1);
      const u16* src;
      if constexpr (AMODE == 0) {
        src = A0 + (size_t)(mb + row) * KK + k;
      } else if constexpr (AMODE == 2) {
        src = (k < 512) ? A0 + (size_t)(mb + row) * 512 + k
                        : A1 + (size_t)(mb + row) * 512 + (k - 512);
      } else {  // AMODE 3: gates
        if (k < 128) {
          int m = mb + row;
          int tok = (t == 0) ? START_TOK : target[m * T_ + (t - 1)];
          src = A0 + tok * E_ + k;
        } else {
          src = A1 + (size_t)(mb + row) * 512 + (k - 128);
        }
      }
      gl16(src, (char*)lA + p * 4096 + tid * 16);
    }
    // ---- stage B (4 passes) ----
#pragma unroll
    for (int p = 0; p < 4; p++) {
      int row = p * 32 + srow;
      int cbs = cbd ^ ((row & 7) << 4);
      int k = kt * 64 + (cbs >> 1);
      gl16(Bt + (size_t)(nb + row) * KK + k, (char*)lB + p * 4096 + tid * 16);
    }
    __syncthreads();
    // ---- compute 2 K-substeps of 32 ----
#pragma unroll
    for (int kk2 = 0; kk2 < 64; kk2 += 32) {
      int cb = (kk2 + lk) * 2;
      bf16x8 af[MA], bfr[4];
#pragma unroll
      for (int a = 0; a < MA; a++) {
        int ra = wm * (BM / 2) + a * 16 + lr;
        af[a] = *(const bf16x8*)((const char*)lA + ra * 128 + (cb ^ ((ra & 7) << 4)));
      }
#pragma unroll
      for (int j = 0; j < 4; j++) {
        int rb = wn * 64 + j * 16 + lr;
        bfr[j] = *(const bf16x8*)((const char*)lB + rb * 128 + (cb ^ ((rb & 7) << 4)));
      }
#pragma unroll
      for (int a = 0; a < MA; a++)
#pragma unroll
        for (int j = 0; j < 4; j++)
          acc[a][j] = __builtin_amdgcn_mfma_f32_16x16x32_bf16(af[a], bfr[j], acc[a][j], 0, 0, 0);
    }
  }

  if constexpr (GATES == 1) {
    // lane holds gates g=frag j at d = (nb/4) + wn*16 + lr  [n'=(d>>4)*64+g*16+(d&15)]
    int d = (nb >> 2) + wn * 16 + lr;
    float bi = bias[d], bfv = bias[512 + d], bg = bias[1024 + d], bo = bias[1536 + d];
#pragma unroll
    for (int a = 0; a < MA; a++) {
#pragma unroll
      for (int r = 0; r < 4; r++) {
        int m = mb + wm * (BM / 2) + a * 16 + rhi * 4 + r;
        size_t idx = (size_t)m * HD_ + d;
        float iv = acc[a][0][r] + bi;
        float fv = acc[a][1][r] + bfv;
        float gv = acc[a][2][r] + bg;
        float ov = acc[a][3][r] + bo;
        float cold = cstate[idx];
        float cn = sigm(fv) * cold + sigm(iv) * tanhf(gv);
        cstate[idx] = cn;
        h_out[idx] = f2bf(sigm(ov) * tanhf(cn));
      }
    }
  } else {
#pragma unroll
    for (int a = 0; a < MA; a++)
#pragma unroll
      for (int j = 0; j < 4; j++) {
        int n = nb + wn * 64 + j * 16 + lr;
        float bv = bias ? bias[n] : 0.f;
#pragma unroll
        for (int r = 0; r < 4; r++) {
          int m = mb + wm * (BM / 2) + a * 16 + rhi * 4 + r;
          float v = acc[a][j][r] + bv;
          if constexpr (ACT == 1) v = tanhf(v);
          if constexpr (OUTF == 1) ((float*)Cv)[(size_t)m * NN + n] = v;
          else                     ((u16*)Cv)[(size_t)m * NN + n] = f2bf(v);
        }
      }
  }
}

// ---------------- attention: score + softmax + ctx ----------------
__global__ __launch_bounds__(256) void score_ctx_kernel(
    const u16* __restrict__ enc_proj, const u16* __restrict__ encB,
    const u16* __restrict__ qb, const float* __restrict__ v_attn,
    float* __restrict__ attn_out, float* __restrict__ attn_ws,
    u16* __restrict__ ctx_bf, int t)
{
  int b = blockIdx.x;
  int tid = threadIdx.x, lane = tid & 63, w = tid >> 6;
  __shared__ float s_att[S_];
  __shared__ float s_sc[S_];

  float qreg[8], vreg[8];
  const u16* qp = qb + (size_t)b * HD_ + lane * 8;
#pragma unroll
  for (int j = 0; j < 8; j++) { qreg[j] = bf2f(qp[j]); vreg[j] = v_attn[lane * 8 + j]; }

  const u16* epb = enc_proj + (size_t)b * S_ * HD_;
  float myscore[6];
#pragma unroll
  for (int i = 0; i < 6; i++) {
    int s = w * 6 + i;
    s16x8 ev = *(const s16x8*)(epb + (size_t)s * HD_ + lane * 8);
    float p = 0.f;
#pragma unroll
    for (int j = 0; j < 8; j++) p += vreg[j] * tanhf(bf2f((u16)ev[j]) + qreg[j]);
#pragma unroll
    for (int m = 1; m < 64; m <<= 1) p += __shfl_xor(p, m, 64);
    myscore[i] = p;
  }
  if (lane == 0) {
#pragma unroll
    for (int i = 0; i < 6; i++) s_sc[w * 6 + i] = myscore[i];
  }
  __syncthreads();

  float mx = -1e30f;
#pragma unroll
  for (int s = 0; s < S_; s++) mx = fmaxf(mx, s_sc[s]);
  if (tid < S_) s_att[tid] = __expf(s_sc[tid] - mx);
  __syncthreads();
  float sum = 0.f;
#pragma unroll
  for (int s = 0; s < S_; s++) sum += s_att[s];
  float inv = 1.f / sum;
  if (tid < S_) {
    float a = s_att[tid] * inv;
    attn_out[((size_t)b * T_ + t) * S_ + tid] = a;
    attn_ws[b * S_ + tid] = a;
  }

  float c0 = 0.f, c1 = 0.f;
  const unsigned* eb = (const unsigned*)(encB + (size_t)b * S_ * HE_) + tid;
#pragma unroll
  for (int s = 0; s < S_; s++) {
    unsigned v = eb[s * (HE_ / 2)];
    float a = s_att[s] * inv;
    c0 += a * bf2f((u16)(v & 0xFFFFu));
    c1 += a * bf2f((u16)(v >> 16));
  }
  ctx_bf[(size_t)b * HE_ + tid * 2]     = f2bf(c0);
  ctx_bf[(size_t)b * HE_ + tid * 2 + 1] = f2bf(c1);
}

// ---------------- output head: softmax + pointer-copy ----------------
__global__ __launch_bounds__(128) void out_kernel(
    const float* __restrict__ logits, const u16* __restrict__ ah,
    const u16* __restrict__ ctxb, const float* __restrict__ w_copy,
    const float* __restrict__ b_copy, const float* __restrict__ attn_ws,
    const int* __restrict__ input_ids, float* __restrict__ outp, int t)
{
  int b = blockIdx.x;
  int tid = threadIdx.x, lane = tid & 63, w = tid >> 6;
  __shared__ float s_l[V_], s_copy[V_], s_small[8];

  float part = 0.f;
  {
    int base = tid * 8;
    const u16* src = (base < 512) ? (ah + (size_t)b * HD_ + base)
                                  : (ctxb + (size_t)b * HE_ + (base - 512));
#pragma unroll
    for (int j = 0; j < 8; j++) part += bf2f(src[j]) * w_copy[base + j];
  }
#pragma unroll
  for (int m = 1; m < 64; m <<= 1) part += __shfl_xor(part, m, 64);
  if (lane == 0) s_small[w] = part;

  if (tid < V_) { s_l[tid] = logits[(size_t)b * 128 + tid]; s_copy[tid] = 0.f; }
  __syncthreads();

  if (tid < S_) atomicAdd(&s_copy[input_ids[b * S_ + tid]], attn_ws[b * S_ + tid]);

  float pc_dot = s_small[0] + s_small[1];
  float pcopy = sigm(pc_dot + b_copy[0]);

  float lv = (tid < V_) ? s_l[tid] : -1e30f;
  float wmx = lv;
#pragma unroll
  for (int m = 1; m < 64; m <<= 1) wmx = fmaxf(wmx, __shfl_xor(wmx, m, 64));
  if (lane == 0) s_small[2 + w] = wmx;
  __syncthreads();
  float mx = fmaxf(s_small[2], s_small[3]);
  float ex = (tid < V_) ? __expf(lv - mx) : 0.f;
  float wsum = ex;
#pragma unroll
  for (int m = 1; m < 64; m <<= 1) wsum += __shfl_xor(wsum, m, 64);
  if (lane == 0) s_small[4 + w] = wsum;
  __syncthreads();
  float inv = 1.f / (s_small[4] + s_small[5]);

  if (tid < V_) {
    float vocab = ex * inv;
    float o = (1.f - pcopy) * vocab + pcopy * s_copy[tid];
    outp[((size_t)b * T_ + t) * V_ + tid] = o;
  }
}

// ---------------- launch ----------------
extern "C" void kernel_launch(void* const* d_in, const int* in_sizes, int n_in,
                              void* d_out, int out_size, void* d_ws, size_t ws_size,
                              hipStream_t stream)
{
  const float* enc      = (const float*)d_in[0];
  const float* enc_fin  = (const float*)d_in[1];
  const int*   target   = (const int*)d_in[2];
  const int*   input_ids= (const int*)d_in[3];
  const float* embed    = (const float*)d_in[4];
  const float* W_init   = (const float*)d_in[5];
  const float* b_init   = (const float*)d_in[6];
  const float* W_ih     = (const float*)d_in[7];
  const float* W_hh     = (const float*)d_in[8];
  const float* b_ih     = (const float*)d_in[9];
  const float* b_hh     = (const float*)d_in[10];
  const float* W_enc    = (const float*)d_in[11];
  const float* W_dec    = (const float*)d_in[12];
  const float* b_attn   = (const float*)d_in[13];
  const float* v_attn   = (const float*)d_in[14];
  const float* W_ap     = (const float*)d_in[15];
  const float* b_ap     = (const float*)d_in[16];
  const float* W_out    = (const float*)d_in[17];
  const float* b_out    = (const float*)d_in[18];
  const float* w_copy   = (const float*)d_in[19];
  const float* b_copy   = (const float*)d_in[20];
  float* outp = (float*)d_out;
  float* attn_out_g = outp + (size_t)B_ * T_ * V_;

  auto align256 = [](size_t x) { return (x + 255) & ~(size_t)255; };
  const size_t persist =
      align256(512 * 512 * 2) * 2 +      // wencT, wdecT
      align256(128 * 512 * 2) +          // woutp
      align256(128 * 4) +                // boutp
      align256(2048 * 4) +               // bsum
      align256((size_t)V_ * E_ * 2) +    // embB
      align256((size_t)512 * 512 * 2) +  // winitB
      align256((size_t)2048 * 640 * 2) + // wgI
      align256((size_t)512 * 1024 * 2) + // wapB
      align256((size_t)B_ * HE_ * 2);    // encfinB
  auto perchunk = [&](int CB) -> size_t {
    return align256((size_t)CB * S_ * HE_ * 2) +
           align256((size_t)CB * S_ * HD_ * 2) +
           align256((size_t)CB * HD_ * 2) * 2 +
           align256((size_t)CB * HD_ * 4) +
           align256((size_t)CB * HD_ * 2) * 3 +
           align256((size_t)CB * 128 * 4) +
           align256((size_t)CB * S_ * 4);
  };
  int NC = 16;
  for (int c : {1, 2, 4, 8, 16}) {
    if (persist + perchunk(B_ / c) <= ws_size) { NC = c; break; }
  }
  const int CB = B_ / NC;

  char* ws = (char*)d_ws;
  size_t off = 0;
  auto alloc = [&](size_t bytes) -> char* {
    char* p = ws + off; off += align256(bytes); return p;
  };
  u16*   wencT   = (u16*)alloc(512 * 512 * 2);
  u16*   wdecT   = (u16*)alloc(512 * 512 * 2);
  u16*   woutp   = (u16*)alloc(128 * 512 * 2);
  float* boutp   = (float*)alloc(128 * 4);
  float* bsum    = (float*)alloc(2048 * 4);
  u16*   embB    = (u16*)alloc((size_t)V_ * E_ * 2);
  u16*   winitB  = (u16*)alloc((size_t)512 * 512 * 2);
  u16*   wgI     = (u16*)alloc((size_t)2048 * 640 * 2);
  u16*   wapB    = (u16*)alloc((size_t)512 * 1024 * 2);
  u16*   encfinB = (u16*)alloc((size_t)B_ * HE_ * 2);
  u16*   encB    = (u16*)alloc((size_t)CB * S_ * HE_ * 2);
  u16*   encproj = (u16*)alloc((size_t)CB * S_ * HD_ * 2);
  u16*   hbuf0   = (u16*)alloc((size_t)CB * HD_ * 2);
  u16*   hbuf1   = (u16*)alloc((size_t)CB * HD_ * 2);
  float* cbuf    = (float*)alloc((size_t)CB * HD_ * 4);
  u16*   qbuf    = (u16*)alloc((size_t)CB * HD_ * 2);
  u16*   ctxbuf  = (u16*)alloc((size_t)CB * HD_ * 2);
  u16*   ahbuf   = (u16*)alloc((size_t)CB * HD_ * 2);
  float* logitsb = (float*)alloc((size_t)CB * 128 * 4);
  float* attnws  = (float*)alloc((size_t)CB * S_ * 4);

  auto cdiv = [](int a, int b) { return (a + b - 1) / b; };
  auto cgrid2 = [&](int n2) { int g = cdiv(n2, 256); return g > 2048 ? 2048 : g; };

  cvt_f2b<<<cgrid2(V_ * E_ / 2), 256, 0, stream>>>(embed, embB, V_ * E_ / 2, 0);
  cvt_f2b<<<cgrid2(512 * 512 / 2), 256, 0, stream>>>(W_init, winitB, 512 * 512 / 2, 0);
  cvt_f2b<<<cgrid2(512 * 1024 / 2), 256, 0, stream>>>(W_ap, wapB, 512 * 1024 / 2, 0);
  cvt_f2b<<<cgrid2(B_ * HE_ / 2), 256, 0, stream>>>(enc_fin, encfinB, B_ * HE_ / 2, 0);
  cvt_gates_w<<<2048, 256, 0, stream>>>(W_ih, W_hh, wgI);
  cvt_transpose<<<cdiv(512 * 512, 256), 256, 0, stream>>>(W_enc, wencT);
  cvt_transpose<<<cdiv(512 * 512, 256), 256, 0, stream>>>(W_dec, wdecT);
  cvt_pad_wout<<<cdiv(128 * 512, 256), 256, 0, stream>>>(W_out, b_out, woutp, boutp);
  bias_sum<<<8, 256, 0, stream>>>(b_ih, b_hh, bsum, 2048);

  u16* hb[2] = { hbuf0, hbuf1 };
  for (int c = 0; c < NC; c++) {
    const size_t row0 = (size_t)c * CB;
    cvt_f2b<<<2048, 256, 0, stream>>>(enc, encB, CB * S_ * HE_ / 2, row0 * S_ * HE_);
    // enc_proj = enc @ W_enc_attn
    gemm_lds<128, 0, 0, 0, 512, 512, 0><<<dim3(CB * S_ / 128, 4), 256, 0, stream>>>(
        encB, nullptr, wencT, nullptr, encproj, nullptr, 0, nullptr, nullptr);
    // h0 = enc_final @ W_init^T + b_init
    gemm_lds<64, 0, 0, 0, 512, 512, 0><<<dim3(CB / 64, 4), 256, 0, stream>>>(
        encfinB + row0 * HE_, nullptr, winitB, b_init, hbuf0, nullptr, 0, nullptr, nullptr);
    hipMemsetAsync(cbuf, 0, (size_t)CB * HD_ * 4, stream);

    for (int t = 0; t < T_; t++) {
      u16* hprev = hb[t & 1];
      u16* hnew  = hb[(t + 1) & 1];
      // fused gates GEMM + LSTM pointwise (interleaved weights)
      gemm_lds<128, 3, 0, 0, 640, 2048, 1><<<dim3(CB / 128, 16), 256, 0, stream>>>(
          embB, hprev, wgI, bsum, nullptr, target + row0 * T_, t, hnew, cbuf);
      // q = h @ W_dec_attn + b_attn
      gemm_lds<64, 0, 0, 0, 512, 512, 0><<<dim3(CB / 64, 4), 256, 0, stream>>>(
          hnew, nullptr, wdecT, b_attn, qbuf, nullptr, 0, nullptr, nullptr);
      score_ctx_kernel<<<CB, 256, 0, stream>>>(
          encproj, encB, qbuf, v_attn,
          attn_out_g + row0 * T_ * S_, attnws, ctxbuf, t);
      // ah = tanh([h, ctx] @ W_ap^T + b_ap)
      gemm_lds<64, 2, 1, 0, 1024, 512, 0><<<dim3(CB / 64, 4), 256, 0, stream>>>(
          hnew, ctxbuf, wapB, b_ap, ahbuf, nullptr, 0, nullptr, nullptr);
      // logits = ah @ W_out_pad^T + b_out_pad (f32 out)
      gemm_lds<64, 0, 0, 1, 512, 128, 0><<<dim3(CB / 64, 1), 256, 0, stream>>>(
          ahbuf, nullptr, woutp, boutp, logitsb, nullptr, 0, nullptr, nullptr);
      out_kernel<<<CB, 128, 0, stream>>>(
          logitsb, ahbuf, ctxbuf, w_copy, b_copy, attnws,
          input_ids + row0 * S_, outp + row0 * T_ * V_, t);
    }
  }
  (void)in_sizes; (void)n_in; (void)out_size;
}